// Round 1
// baseline (122.979 us; speedup 1.0000x reference)
//
#include <hip/hip_runtime.h>

#define Bn 32
#define Tn 256
#define Cn 512
#define Ln 25

typedef _Float16 h8 __attribute__((ext_vector_type(8)));
typedef _Float16 h4 __attribute__((ext_vector_type(4)));
typedef __attribute__((ext_vector_type(4))) float f32x4;

#define SCALE2LOG2E 2.885390081777927f   // 2*log2(e)

#if __has_builtin(__builtin_amdgcn_exp2f)
#define EXP2(x) __builtin_amdgcn_exp2f(x)
#else
#define EXP2(x) __expf(0.69314718056f * (x))
#endif

// sum across 16-lane groups on VALU pipe: xor1, xor2, xor7, xor15 pairings
#define DPP_ADD(v, ctrl) \
    ((v) + __int_as_float(__builtin_amdgcn_update_dpp(0, __float_as_int(v), ctrl, 0xf, 0xf, true)))

// K0: convert W fp32->fp16 + precompute EP = exp(2*pos) (fp32).
// A conversion is fused into k_gemm's staging now (saves a 25 MB round-trip).
#define NW_OCT (Cn * Cn / 8)                // 32768
#define NP_OCT (Ln * Cn / 8)                // 1600
__global__ __launch_bounds__(256) void k_convert(
        const float* __restrict__ W, const float* __restrict__ pos,
        _Float16* __restrict__ W2, float* __restrict__ EP) {
    int idx = blockIdx.x * 256 + threadIdx.x;
    if (idx < NW_OCT) {
        int off = idx * 8;
        float4 v0 = *(const float4*)&W[off];
        float4 v1 = *(const float4*)&W[off + 4];
        h8 o;
        o[0] = (_Float16)v0.x; o[1] = (_Float16)v0.y;
        o[2] = (_Float16)v0.z; o[3] = (_Float16)v0.w;
        o[4] = (_Float16)v1.x; o[5] = (_Float16)v1.y;
        o[6] = (_Float16)v1.z; o[7] = (_Float16)v1.w;
        *(h8*)&W2[off] = o;
    } else if (idx < NW_OCT + NP_OCT) {
        int off = (idx - NW_OCT) * 8;
        float4 v0 = *(const float4*)&pos[off];
        float4 v1 = *(const float4*)&pos[off + 4];
        float4 t0, t1;
        t0.x = EXP2(SCALE2LOG2E * v0.x); t0.y = EXP2(SCALE2LOG2E * v0.y);
        t0.z = EXP2(SCALE2LOG2E * v0.z); t0.w = EXP2(SCALE2LOG2E * v0.w);
        t1.x = EXP2(SCALE2LOG2E * v1.x); t1.y = EXP2(SCALE2LOG2E * v1.y);
        t1.z = EXP2(SCALE2LOG2E * v1.z); t1.w = EXP2(SCALE2LOG2E * v1.w);
        *(float4*)&EP[off] = t0;
        *(float4*)&EP[off + 4] = t1;
    }
}

// K1: wf[m][n] = sum_k A[m][k]*W2[n][k] + bias[n]   (fp16 MFMA, K=512)
// A is read fp32 and converted in-register while staging to LDS (same RTN
// rounding as the old separate convert kernel -> bit-identical wf).
#define BM 128
#define BN 64
#define BKg 64
__global__ __launch_bounds__(256) void k_gemm(
        const float* __restrict__ A, const _Float16* __restrict__ W2,
        const float* __restrict__ bias, _Float16* __restrict__ wf) {
    __shared__ _Float16 As[BM * BKg];   // 16 KB
    __shared__ _Float16 Ws[BN * BKg];   // 8 KB
    const int tid  = threadIdx.x;
    const int lane = tid & 63;
    const int wv   = tid >> 6;
    const int m0 = blockIdx.y * BM;
    const int n0 = blockIdx.x * BN;
    const int wm = (wv >> 1) * 64;
    const int wn = (wv & 1) * 32;
    const int r = lane & 15, q = lane >> 4;

    const float* gA[4];
    const _Float16* gW[2];
    #pragma unroll
    for (int rr = 0; rr < 4; ++rr) {
        int p = rr * 256 + tid;
        int row = p >> 3, pk = p & 7;
        int lk = pk ^ (row & 7);
        gA[rr] = A + (size_t)(m0 + row) * Cn + lk * 8;
    }
    #pragma unroll
    for (int rr = 0; rr < 2; ++rr) {
        int p = rr * 256 + tid;
        int row = p >> 3, pk = p & 7;
        int lk = pk ^ (row & 7);
        gW[rr] = W2 + (size_t)(n0 + row) * Cn + lk * 8;
    }

    f32x4 acc[4][2];
    #pragma unroll
    for (int mi = 0; mi < 4; ++mi)
        #pragma unroll
        for (int ni = 0; ni < 2; ++ni) acc[mi][ni] = (f32x4){0.f, 0.f, 0.f, 0.f};

    for (int kt = 0; kt < Cn / BKg; ++kt) {
        // issue fp32 A loads early: they hide under the previous step's MFMA
        float4 va[4], vb[4];
        #pragma unroll
        for (int rr = 0; rr < 4; ++rr) {
            va[rr] = *(const float4*)gA[rr];
            vb[rr] = *(const float4*)(gA[rr] + 4);
            gA[rr] += BKg;
        }
        __syncthreads();
        #pragma unroll
        for (int rr = 0; rr < 2; ++rr) {
            __builtin_amdgcn_global_load_lds(
                (const __attribute__((address_space(1))) unsigned int*)gW[rr],
                (__attribute__((address_space(3))) unsigned int*)(Ws + (rr * 256 + wv * 64) * 8),
                16, 0, 0);
            gW[rr] += BKg;
        }
        #pragma unroll
        for (int rr = 0; rr < 4; ++rr) {
            h8 o;
            o[0] = (_Float16)va[rr].x; o[1] = (_Float16)va[rr].y;
            o[2] = (_Float16)va[rr].z; o[3] = (_Float16)va[rr].w;
            o[4] = (_Float16)vb[rr].x; o[5] = (_Float16)vb[rr].y;
            o[6] = (_Float16)vb[rr].z; o[7] = (_Float16)vb[rr].w;
            *(h8*)&As[(rr * 256 + tid) * 8] = o;
        }
        __syncthreads();

        h8 af[4][2], bfr[2][2];
        #pragma unroll
        for (int mi = 0; mi < 4; ++mi)
            #pragma unroll
            for (int kk = 0; kk < 2; ++kk) {
                int row = wm + mi * 16 + r;
                int phys = (kk * 4 + q) ^ (r & 7);
                af[mi][kk] = *(const h8*)&As[row * BKg + phys * 8];
            }
        #pragma unroll
        for (int ni = 0; ni < 2; ++ni)
            #pragma unroll
            for (int kk = 0; kk < 2; ++kk) {
                int row = wn + ni * 16 + r;
                int phys = (kk * 4 + q) ^ (r & 7);
                bfr[ni][kk] = *(const h8*)&Ws[row * BKg + phys * 8];
            }
        #pragma unroll
        for (int kk = 0; kk < 2; ++kk)
            #pragma unroll
            for (int mi = 0; mi < 4; ++mi)
                #pragma unroll
                for (int ni = 0; ni < 2; ++ni)
                    acc[mi][ni] = __builtin_amdgcn_mfma_f32_16x16x32_f16(
                        af[mi][kk], bfr[ni][kk], acc[mi][ni], 0, 0, 0);
    }

    #pragma unroll
    for (int ni = 0; ni < 2; ++ni) {
        const float bv = bias[n0 + wn + ni * 16 + r];
        #pragma unroll
        for (int mi = 0; mi < 4; ++mi)
            #pragma unroll
            for (int reg = 0; reg < 4; ++reg) {
                int row = m0 + wm + mi * 16 + q * 4 + reg;
                int col = n0 + wn + ni * 16 + r;
                wf[(size_t)row * Cn + col] = (_Float16)(acc[mi][ni][reg] + bv);
            }
    }
}

// K2: scores via exp form of tanh addition:
//   sum_c aw*tanh(w+p) = sum_c aw - 2*sum_c aw*rcp(1 + e^{2w} e^{2p})
// The sum_c aw constant (and atten_b) is t-invariant -> cancels in softmax.
// Inner body per (l, 4c): 4 fma + 4 rcp + 4 fma + 4 dpp  (was 16 VALU + 4 rcp + 4 dpp).
__global__ __launch_bounds__(512) void k_scores(
        const _Float16* __restrict__ wf, const float* __restrict__ EP,
        const float* __restrict__ aw, float* __restrict__ scores) {
    __shared__ float part[4 * Ln * 8];       // 3.2 KB
    const int tid  = threadIdx.x;
    const int lane = tid & 63;
    const int wv   = tid >> 6;
    const int tl   = wv >> 1;                // local t 0..3
    const int ch   = wv & 1;                 // c half
    const int t    = blockIdx.x * 4 + tl;
    const int b    = blockIdx.y;
    const int co   = ch * 256 + lane * 4;

    const h4 wh = *(const h4*)&wf[(size_t)(b * Tn + t) * Cn + co];
    float4 ew;
    ew.x = EXP2(SCALE2LOG2E * (float)wh[0]);
    ew.y = EXP2(SCALE2LOG2E * (float)wh[1]);
    ew.z = EXP2(SCALE2LOG2E * (float)wh[2]);
    ew.w = EXP2(SCALE2LOG2E * (float)wh[3]);
    float4 a = *(const float4*)&aw[co];
    a.x *= -2.f; a.y *= -2.f; a.z *= -2.f; a.w *= -2.f;

    const float* pp = EP + co;
    float* prt = &part[tl * Ln * 8 + ch * 4 + (lane >> 4)];
    const bool writer = ((lane & 15) == 0);

    #pragma unroll
    for (int lo = 0; lo < 5; ++lo) {
        float4 pv[5];
        #pragma unroll
        for (int j = 0; j < 5; ++j)
            pv[j] = *(const float4*)(pp + (lo * 5 + j) * Cn);
        #pragma unroll
        for (int j = 0; j < 5; ++j) {
            const float4 p = pv[j];
            float d0 = fmaf(ew.x, p.x, 1.f);
            float s  = a.x * __builtin_amdgcn_rcpf(d0);
            float d1 = fmaf(ew.y, p.y, 1.f);
            s = fmaf(a.y, __builtin_amdgcn_rcpf(d1), s);
            float d2 = fmaf(ew.z, p.z, 1.f);
            s = fmaf(a.z, __builtin_amdgcn_rcpf(d2), s);
            float d3 = fmaf(ew.w, p.w, 1.f);
            s = fmaf(a.w, __builtin_amdgcn_rcpf(d3), s);
            s = DPP_ADD(s, 0xB1);    // xor 1
            s = DPP_ADD(s, 0x4E);    // xor 2
            s = DPP_ADD(s, 0x141);   // row_half_mirror (xor 7)
            s = DPP_ADD(s, 0x140);   // row_mirror (xor 15)
            if (writer) prt[(lo * 5 + j) * 8] = s;
        }
    }
    __syncthreads();
    if (tid < 4 * Ln) {
        int tl2 = tid / Ln, l2 = tid - tl2 * Ln;
        const float* q = &part[(tl2 * Ln + l2) * 8];
        float v = ((q[0] + q[1]) + (q[2] + q[3])) + ((q[4] + q[5]) + (q[6] + q[7]));
        scores[(b * Ln + l2) * Tn + blockIdx.x * 4 + tl2] = v;
    }
}

// K3: softmax over t; out[b][l][c] = sum_t p[l][t] * wf[b][t][c]; wf fp16 reads.
__global__ __launch_bounds__(512) void k_pvam(
        const _Float16* __restrict__ wf, const float* __restrict__ scores,
        float* __restrict__ out) {
    __shared__ float buf[8 * Ln * 64];       // 51.2 KB: scores staging, then reduction
    __shared__ float pT[Tn][28];             // 28.7 KB
    const int tid = threadIdx.x;
    const int cx  = blockIdx.x;
    const int b   = blockIdx.y;

    const float* sc = scores + b * Ln * Tn;
    for (int i = tid * 4; i < Ln * Tn; i += 2048)
        *(float4*)&buf[i] = *(const float4*)&sc[i];
    __syncthreads();

    const int lane = tid & 63;
    const int wv   = tid >> 6;

    for (int l = wv; l < Ln; l += 8) {
        float v0 = buf[l * Tn + lane];
        float v1 = buf[l * Tn + 64 + lane];
        float v2 = buf[l * Tn + 128 + lane];
        float v3 = buf[l * Tn + 192 + lane];
        float m = fmaxf(fmaxf(v0, v1), fmaxf(v2, v3));
        #pragma unroll
        for (int o = 32; o > 0; o >>= 1) m = fmaxf(m, __shfl_xor(m, o));
        float e0 = __expf(v0 - m), e1 = __expf(v1 - m);
        float e2 = __expf(v2 - m), e3 = __expf(v3 - m);
        float s = e0 + e1 + e2 + e3;
        #pragma unroll
        for (int o = 32; o > 0; o >>= 1) s += __shfl_xor(s, o);
        float rs = __builtin_amdgcn_rcpf(s);
        pT[lane][l]       = e0 * rs;
        pT[64 + lane][l]  = e1 * rs;
        pT[128 + lane][l] = e2 * rs;
        pT[192 + lane][l] = e3 * rs;
    }
    __syncthreads();

    const int c = cx * 64 + lane;
    float acc[Ln];
    #pragma unroll
    for (int l = 0; l < Ln; ++l) acc[l] = 0.f;

    const _Float16* wfp = wf + (size_t)(b * Tn + wv * 32) * Cn + c;
    for (int tt = 0; tt < 32; ++tt) {
        float w = (float)wfp[(size_t)tt * Cn];
        const float* pp = &pT[wv * 32 + tt][0];
        float p[Ln];
        *(float4*)&p[0]  = *(const float4*)&pp[0];
        *(float4*)&p[4]  = *(const float4*)&pp[4];
        *(float4*)&p[8]  = *(const float4*)&pp[8];
        *(float4*)&p[12] = *(const float4*)&pp[12];
        *(float4*)&p[16] = *(const float4*)&pp[16];
        *(float4*)&p[20] = *(const float4*)&pp[20];
        p[24] = pp[24];
        #pragma unroll
        for (int l = 0; l < Ln; ++l) acc[l] = fmaf(p[l], w, acc[l]);
    }

    __syncthreads();
    #pragma unroll
    for (int l = 0; l < Ln; ++l)
        buf[(wv * Ln + l) * 64 + lane] = acc[l];
    __syncthreads();
    for (int idx = tid; idx < Ln * 64; idx += 512) {
        int l = idx >> 6, cc = idx & 63;
        float v = 0.f;
        #pragma unroll
        for (int w = 0; w < 8; ++w) v += buf[(w * Ln + l) * 64 + cc];
        out[(b * Ln + l) * Cn + cx * 64 + cc] = v;
    }
}

extern "C" void kernel_launch(void* const* d_in, const int* in_sizes, int n_in,
                              void* d_out, int out_size, void* d_ws, size_t ws_size,
                              hipStream_t stream) {
    const float* A    = (const float*)d_in[0];
    const float* W    = (const float*)d_in[1];
    const float* bias = (const float*)d_in[2];
    const float* pos  = (const float*)d_in[3];
    const float* aw   = (const float*)d_in[4];

    char* ws = (char*)d_ws;
    _Float16*  wf     = (_Float16*)ws;                       // 8.39 MB
    float*     scores = (float*)(ws + 8388608ull);           // 0.82 MB
    _Float16*  W2     = (_Float16*)(ws + 9207808ull);        // 0.52 MB
    float*     EP     = (float*)(ws + 9732096ull);           // 51.2 KB exp(2*pos)
    float* out = (float*)d_out;

    const int nconv = (NW_OCT + NP_OCT + 255) / 256;         // 135 blocks
    k_convert<<<nconv, 256, 0, stream>>>(W, pos, W2, EP);
    k_gemm<<<dim3(Cn / BN, (Bn * Tn) / BM), 256, 0, stream>>>(A, W2, bias, wf);
    k_scores<<<dim3(Tn / 4, Bn), 512, 0, stream>>>(wf, EP, aw, scores);
    k_pvam<<<dim3(Cn / 64, Bn), 512, 0, stream>>>(wf, scores, out);
}

// Round 2
// 120.418 us; speedup vs baseline: 1.0213x; 1.0213x over previous
//
#include <hip/hip_runtime.h>

#define Bn 32
#define Tn 256
#define Cn 512
#define Ln 25

typedef _Float16 h8 __attribute__((ext_vector_type(8)));
typedef _Float16 h4 __attribute__((ext_vector_type(4)));
typedef __attribute__((ext_vector_type(4))) float f32x4;

#define SCALE2LOG2E 2.885390081777927f   // 2*log2(e)

#if __has_builtin(__builtin_amdgcn_exp2f)
#define EXP2(x) __builtin_amdgcn_exp2f(x)
#else
#define EXP2(x) __expf(0.69314718056f * (x))
#endif

// sum across 16-lane groups on VALU pipe: xor1, xor2, xor7, xor15 pairings
#define DPP_ADD(v, ctrl) \
    ((v) + __int_as_float(__builtin_amdgcn_update_dpp(0, __float_as_int(v), ctrl, 0xf, 0xf, true)))

#define NP_OCT (Ln * Cn / 8)                // 1600

// K1: wf[m][n] = sum_k A[m][k]*W[n][k] + bias[n]   (fp16 MFMA, K=512)
// Both A and W are read fp32 and converted in-register while staging to LDS
// (same RTN rounding as the old separate convert kernel -> bit-identical wf).
// EP = exp(2*pos) is computed by 7 of the 512 blocks before their GEMM work,
// eliminating the former k_convert launch entirely.
#define BM 128
#define BN 64
#define BKg 64
__global__ __launch_bounds__(256) void k_gemm(
        const float* __restrict__ A, const float* __restrict__ W,
        const float* __restrict__ bias, const float* __restrict__ pos,
        _Float16* __restrict__ wf, float* __restrict__ EP) {
    __shared__ _Float16 As[BM * BKg];   // 16 KB
    __shared__ _Float16 Ws[BN * BKg];   // 8 KB
    const int tid  = threadIdx.x;

    // fused EP precompute (tiny: 25*512 floats), no sync needed before GEMM
    if (blockIdx.y == 0 && blockIdx.x < 7) {
        int idx = blockIdx.x * 256 + tid;
        if (idx < NP_OCT) {
            int off = idx * 8;
            float4 v0 = *(const float4*)&pos[off];
            float4 v1 = *(const float4*)&pos[off + 4];
            float4 t0, t1;
            t0.x = EXP2(SCALE2LOG2E * v0.x); t0.y = EXP2(SCALE2LOG2E * v0.y);
            t0.z = EXP2(SCALE2LOG2E * v0.z); t0.w = EXP2(SCALE2LOG2E * v0.w);
            t1.x = EXP2(SCALE2LOG2E * v1.x); t1.y = EXP2(SCALE2LOG2E * v1.y);
            t1.z = EXP2(SCALE2LOG2E * v1.z); t1.w = EXP2(SCALE2LOG2E * v1.w);
            *(float4*)&EP[off] = t0;
            *(float4*)&EP[off + 4] = t1;
        }
    }

    const int lane = tid & 63;
    const int wv   = tid >> 6;
    const int m0 = blockIdx.y * BM;
    const int n0 = blockIdx.x * BN;
    const int wm = (wv >> 1) * 64;
    const int wn = (wv & 1) * 32;
    const int r = lane & 15, q = lane >> 4;

    const float* gA[4];
    const float* gW[2];
    #pragma unroll
    for (int rr = 0; rr < 4; ++rr) {
        int p = rr * 256 + tid;
        int row = p >> 3, pk = p & 7;
        int lk = pk ^ (row & 7);
        gA[rr] = A + (size_t)(m0 + row) * Cn + lk * 8;
    }
    #pragma unroll
    for (int rr = 0; rr < 2; ++rr) {
        int p = rr * 256 + tid;
        int row = p >> 3, pk = p & 7;
        int lk = pk ^ (row & 7);
        gW[rr] = W + (size_t)(n0 + row) * Cn + lk * 8;
    }

    f32x4 acc[4][2];
    #pragma unroll
    for (int mi = 0; mi < 4; ++mi)
        #pragma unroll
        for (int ni = 0; ni < 2; ++ni) acc[mi][ni] = (f32x4){0.f, 0.f, 0.f, 0.f};

    // prologue: prefetch k-step 0 into registers
    float4 va[4], vb[4], vc[2], vd[2];
    #pragma unroll
    for (int rr = 0; rr < 4; ++rr) {
        va[rr] = *(const float4*)gA[rr];
        vb[rr] = *(const float4*)(gA[rr] + 4);
        gA[rr] += BKg;
    }
    #pragma unroll
    for (int rr = 0; rr < 2; ++rr) {
        vc[rr] = *(const float4*)gW[rr];
        vd[rr] = *(const float4*)(gW[rr] + 4);
        gW[rr] += BKg;
    }

    for (int kt = 0; kt < Cn / BKg; ++kt) {
        // convert current step to fp16 (frees va/vb/vc/vd for the prefetch)
        h8 oa[4], ow[2];
        #pragma unroll
        for (int rr = 0; rr < 4; ++rr) {
            oa[rr][0] = (_Float16)va[rr].x; oa[rr][1] = (_Float16)va[rr].y;
            oa[rr][2] = (_Float16)va[rr].z; oa[rr][3] = (_Float16)va[rr].w;
            oa[rr][4] = (_Float16)vb[rr].x; oa[rr][5] = (_Float16)vb[rr].y;
            oa[rr][6] = (_Float16)vb[rr].z; oa[rr][7] = (_Float16)vb[rr].w;
        }
        #pragma unroll
        for (int rr = 0; rr < 2; ++rr) {
            ow[rr][0] = (_Float16)vc[rr].x; ow[rr][1] = (_Float16)vc[rr].y;
            ow[rr][2] = (_Float16)vc[rr].z; ow[rr][3] = (_Float16)vc[rr].w;
            ow[rr][4] = (_Float16)vd[rr].x; ow[rr][5] = (_Float16)vd[rr].y;
            ow[rr][6] = (_Float16)vd[rr].z; ow[rr][7] = (_Float16)vd[rr].w;
        }

        __syncthreads();   // previous step's LDS consumers are done

        // issue next step's global loads now: they land during this step's MFMAs
        if (kt + 1 < Cn / BKg) {
            #pragma unroll
            for (int rr = 0; rr < 4; ++rr) {
                va[rr] = *(const float4*)gA[rr];
                vb[rr] = *(const float4*)(gA[rr] + 4);
                gA[rr] += BKg;
            }
            #pragma unroll
            for (int rr = 0; rr < 2; ++rr) {
                vc[rr] = *(const float4*)gW[rr];
                vd[rr] = *(const float4*)(gW[rr] + 4);
                gW[rr] += BKg;
            }
        }

        #pragma unroll
        for (int rr = 0; rr < 4; ++rr)
            *(h8*)&As[(rr * 256 + tid) * 8] = oa[rr];
        #pragma unroll
        for (int rr = 0; rr < 2; ++rr)
            *(h8*)&Ws[(rr * 256 + tid) * 8] = ow[rr];
        __syncthreads();

        h8 af[4][2], bfr[2][2];
        #pragma unroll
        for (int mi = 0; mi < 4; ++mi)
            #pragma unroll
            for (int kk = 0; kk < 2; ++kk) {
                int row = wm + mi * 16 + r;
                int phys = (kk * 4 + q) ^ (r & 7);
                af[mi][kk] = *(const h8*)&As[row * BKg + phys * 8];
            }
        #pragma unroll
        for (int ni = 0; ni < 2; ++ni)
            #pragma unroll
            for (int kk = 0; kk < 2; ++kk) {
                int row = wn + ni * 16 + r;
                int phys = (kk * 4 + q) ^ (r & 7);
                bfr[ni][kk] = *(const h8*)&Ws[row * BKg + phys * 8];
            }
        #pragma unroll
        for (int kk = 0; kk < 2; ++kk)
            #pragma unroll
            for (int mi = 0; mi < 4; ++mi)
                #pragma unroll
                for (int ni = 0; ni < 2; ++ni)
                    acc[mi][ni] = __builtin_amdgcn_mfma_f32_16x16x32_f16(
                        af[mi][kk], bfr[ni][kk], acc[mi][ni], 0, 0, 0);
    }

    #pragma unroll
    for (int ni = 0; ni < 2; ++ni) {
        const float bv = bias[n0 + wn + ni * 16 + r];
        #pragma unroll
        for (int mi = 0; mi < 4; ++mi)
            #pragma unroll
            for (int reg = 0; reg < 4; ++reg) {
                int row = m0 + wm + mi * 16 + q * 4 + reg;
                int col = n0 + wn + ni * 16 + r;
                wf[(size_t)row * Cn + col] = (_Float16)(acc[mi][ni][reg] + bv);
            }
    }
}

// K2: scores via exp form of tanh addition:
//   sum_c aw*tanh(w+p) = sum_c aw - 2*sum_c aw*rcp(1 + e^{2w} e^{2p})
// The sum_c aw constant (and atten_b) is t-invariant -> cancels in softmax.
__global__ __launch_bounds__(512) void k_scores(
        const _Float16* __restrict__ wf, const float* __restrict__ EP,
        const float* __restrict__ aw, float* __restrict__ scores) {
    __shared__ float part[4 * Ln * 8];       // 3.2 KB
    const int tid  = threadIdx.x;
    const int lane = tid & 63;
    const int wv   = tid >> 6;
    const int tl   = wv >> 1;                // local t 0..3
    const int ch   = wv & 1;                 // c half
    const int t    = blockIdx.x * 4 + tl;
    const int b    = blockIdx.y;
    const int co   = ch * 256 + lane * 4;

    const h4 wh = *(const h4*)&wf[(size_t)(b * Tn + t) * Cn + co];
    float4 ew;
    ew.x = EXP2(SCALE2LOG2E * (float)wh[0]);
    ew.y = EXP2(SCALE2LOG2E * (float)wh[1]);
    ew.z = EXP2(SCALE2LOG2E * (float)wh[2]);
    ew.w = EXP2(SCALE2LOG2E * (float)wh[3]);
    float4 a = *(const float4*)&aw[co];
    a.x *= -2.f; a.y *= -2.f; a.z *= -2.f; a.w *= -2.f;

    const float* pp = EP + co;
    float* prt = &part[tl * Ln * 8 + ch * 4 + (lane >> 4)];
    const bool writer = ((lane & 15) == 0);

    #pragma unroll
    for (int lo = 0; lo < 5; ++lo) {
        float4 pv[5];
        #pragma unroll
        for (int j = 0; j < 5; ++j)
            pv[j] = *(const float4*)(pp + (lo * 5 + j) * Cn);
        #pragma unroll
        for (int j = 0; j < 5; ++j) {
            const float4 p = pv[j];
            float d0 = fmaf(ew.x, p.x, 1.f);
            float s  = a.x * __builtin_amdgcn_rcpf(d0);
            float d1 = fmaf(ew.y, p.y, 1.f);
            s = fmaf(a.y, __builtin_amdgcn_rcpf(d1), s);
            float d2 = fmaf(ew.z, p.z, 1.f);
            s = fmaf(a.z, __builtin_amdgcn_rcpf(d2), s);
            float d3 = fmaf(ew.w, p.w, 1.f);
            s = fmaf(a.w, __builtin_amdgcn_rcpf(d3), s);
            s = DPP_ADD(s, 0xB1);    // xor 1
            s = DPP_ADD(s, 0x4E);    // xor 2
            s = DPP_ADD(s, 0x141);   // row_half_mirror (xor 7)
            s = DPP_ADD(s, 0x140);   // row_mirror (xor 15)
            if (writer) prt[(lo * 5 + j) * 8] = s;
        }
    }
    __syncthreads();
    if (tid < 4 * Ln) {
        int tl2 = tid / Ln, l2 = tid - tl2 * Ln;
        const float* q = &part[(tl2 * Ln + l2) * 8];
        float v = ((q[0] + q[1]) + (q[2] + q[3])) + ((q[4] + q[5]) + (q[6] + q[7]));
        scores[(b * Ln + l2) * Tn + blockIdx.x * 4 + tl2] = v;
    }
}

// K3: softmax over t; out[b][l][c] = sum_t p[l][t] * wf[b][t][c]; wf fp16 reads.
__global__ __launch_bounds__(512) void k_pvam(
        const _Float16* __restrict__ wf, const float* __restrict__ scores,
        float* __restrict__ out) {
    __shared__ float buf[8 * Ln * 64];       // 51.2 KB: scores staging, then reduction
    __shared__ float pT[Tn][28];             // 28.7 KB
    const int tid = threadIdx.x;
    const int cx  = blockIdx.x;
    const int b   = blockIdx.y;

    const float* sc = scores + b * Ln * Tn;
    for (int i = tid * 4; i < Ln * Tn; i += 2048)
        *(float4*)&buf[i] = *(const float4*)&sc[i];
    __syncthreads();

    const int lane = tid & 63;
    const int wv   = tid >> 6;

    for (int l = wv; l < Ln; l += 8) {
        float v0 = buf[l * Tn + lane];
        float v1 = buf[l * Tn + 64 + lane];
        float v2 = buf[l * Tn + 128 + lane];
        float v3 = buf[l * Tn + 192 + lane];
        float m = fmaxf(fmaxf(v0, v1), fmaxf(v2, v3));
        #pragma unroll
        for (int o = 32; o > 0; o >>= 1) m = fmaxf(m, __shfl_xor(m, o));
        float e0 = __expf(v0 - m), e1 = __expf(v1 - m);
        float e2 = __expf(v2 - m), e3 = __expf(v3 - m);
        float s = e0 + e1 + e2 + e3;
        #pragma unroll
        for (int o = 32; o > 0; o >>= 1) s += __shfl_xor(s, o);
        float rs = __builtin_amdgcn_rcpf(s);
        pT[lane][l]       = e0 * rs;
        pT[64 + lane][l]  = e1 * rs;
        pT[128 + lane][l] = e2 * rs;
        pT[192 + lane][l] = e3 * rs;
    }
    __syncthreads();

    const int c = cx * 64 + lane;
    float acc[Ln];
    #pragma unroll
    for (int l = 0; l < Ln; ++l) acc[l] = 0.f;

    const _Float16* wfp = wf + (size_t)(b * Tn + wv * 32) * Cn + c;
    for (int tt = 0; tt < 32; ++tt) {
        float w = (float)wfp[(size_t)tt * Cn];
        const float* pp = &pT[wv * 32 + tt][0];
        float p[Ln];
        *(float4*)&p[0]  = *(const float4*)&pp[0];
        *(float4*)&p[4]  = *(const float4*)&pp[4];
        *(float4*)&p[8]  = *(const float4*)&pp[8];
        *(float4*)&p[12] = *(const float4*)&pp[12];
        *(float4*)&p[16] = *(const float4*)&pp[16];
        *(float4*)&p[20] = *(const float4*)&pp[20];
        p[24] = pp[24];
        #pragma unroll
        for (int l = 0; l < Ln; ++l) acc[l] = fmaf(p[l], w, acc[l]);
    }

    __syncthreads();
    #pragma unroll
    for (int l = 0; l < Ln; ++l)
        buf[(wv * Ln + l) * 64 + lane] = acc[l];
    __syncthreads();
    for (int idx = tid; idx < Ln * 64; idx += 512) {
        int l = idx >> 6, cc = idx & 63;
        float v = 0.f;
        #pragma unroll
        for (int w = 0; w < 8; ++w) v += buf[(w * Ln + l) * 64 + cc];
        out[(b * Ln + l) * Cn + cx * 64 + cc] = v;
    }
}

extern "C" void kernel_launch(void* const* d_in, const int* in_sizes, int n_in,
                              void* d_out, int out_size, void* d_ws, size_t ws_size,
                              hipStream_t stream) {
    const float* A    = (const float*)d_in[0];
    const float* W    = (const float*)d_in[1];
    const float* bias = (const float*)d_in[2];
    const float* pos  = (const float*)d_in[3];
    const float* aw   = (const float*)d_in[4];

    char* ws = (char*)d_ws;
    _Float16*  wf     = (_Float16*)ws;                       // 8.39 MB
    float*     scores = (float*)(ws + 8388608ull);           // 0.82 MB
    float*     EP     = (float*)(ws + 9207808ull);           // 51.2 KB exp(2*pos)
    float* out = (float*)d_out;

    k_gemm<<<dim3(Cn / BN, (Bn * Tn) / BM), 256, 0, stream>>>(A, W, bias, pos, wf, EP);
    k_scores<<<dim3(Tn / 4, Bn), 512, 0, stream>>>(wf, EP, aw, scores);
    k_pvam<<<dim3(Cn / 64, Bn), 512, 0, stream>>>(wf, scores, out);
}

// Round 3
// 113.448 us; speedup vs baseline: 1.0840x; 1.0614x over previous
//
#include <hip/hip_runtime.h>

#define Bn 32
#define Tn 256
#define Cn 512
#define Ln 25

typedef _Float16 h8 __attribute__((ext_vector_type(8)));
typedef _Float16 h4 __attribute__((ext_vector_type(4)));
typedef __attribute__((ext_vector_type(4))) float f32x4;

#define SCALE2LOG2E 2.885390081777927f   // 2*log2(e)

#if __has_builtin(__builtin_amdgcn_exp2f)
#define EXP2(x) __builtin_amdgcn_exp2f(x)
#else
#define EXP2(x) __expf(0.69314718056f * (x))
#endif

// sum across 16-lane groups on VALU pipe: xor1, xor2, xor7, xor15 pairings
#define DPP_ADD(v, ctrl) \
    ((v) + __int_as_float(__builtin_amdgcn_update_dpp(0, __float_as_int(v), ctrl, 0xf, 0xf, true)))

#define NP_OCT (Ln * Cn / 8)                // 1600

// K1: wf[m][n] = sum_k A[m][k]*W[n][k] + bias[n]   (fp16 MFMA, K=512)
// A and W read fp32, converted in-register while staging to LDS (RTN -> wf
// bit-identical to the old separate-convert pipeline).
// XCD-aware swizzle: each XCD owns 8 m-tiles x all 8 n-tiles, so its A
// working set is 2 MB fp32 -> L2-resident; A is fetched from HBM exactly once
// chip-wide (was ~8x via L3 with the default round-robin mapping).
#define BM 128
#define BN 64
#define BKg 64
__global__ __launch_bounds__(256) void k_gemm(
        const float* __restrict__ A, const float* __restrict__ W,
        const float* __restrict__ bias, const float* __restrict__ pos,
        _Float16* __restrict__ wf, float* __restrict__ EP) {
    __shared__ _Float16 As[BM * BKg];   // 16 KB
    __shared__ _Float16 Ws[BN * BKg];   // 8 KB
    const int tid  = threadIdx.x;
    const int f    = blockIdx.x;        // 0..511, XCD = f & 7 (round-robin)

    // fused EP precompute (tiny: 25*512 floats), no sync needed before GEMM
    if (f < 7) {
        int idx = f * 256 + tid;
        if (idx < NP_OCT) {
            int off = idx * 8;
            float4 v0 = *(const float4*)&pos[off];
            float4 v1 = *(const float4*)&pos[off + 4];
            float4 t0, t1;
            t0.x = EXP2(SCALE2LOG2E * v0.x); t0.y = EXP2(SCALE2LOG2E * v0.y);
            t0.z = EXP2(SCALE2LOG2E * v0.z); t0.w = EXP2(SCALE2LOG2E * v0.w);
            t1.x = EXP2(SCALE2LOG2E * v1.x); t1.y = EXP2(SCALE2LOG2E * v1.y);
            t1.z = EXP2(SCALE2LOG2E * v1.z); t1.w = EXP2(SCALE2LOG2E * v1.w);
            *(float4*)&EP[off] = t0;
            *(float4*)&EP[off + 4] = t1;
        }
    }

    // bijective XCD swizzle: xcd r gets m-tiles [8r, 8r+8) x all 8 n-tiles
    const int xcd = f & 7;
    const int s   = f >> 3;              // 0..63 slot on this xcd
    const int my  = xcd * 8 + (s >> 3);  // m-tile 0..63
    const int nx  = s & 7;               // n-tile 0..7

    const int lane = tid & 63;
    const int wv   = tid >> 6;
    const int m0 = my * BM;
    const int n0 = nx * BN;
    const int wm = (wv >> 1) * 64;
    const int wn = (wv & 1) * 32;
    const int r = lane & 15, q = lane >> 4;

    const float* gA[4];
    const float* gW[2];
    #pragma unroll
    for (int rr = 0; rr < 4; ++rr) {
        int p = rr * 256 + tid;
        int row = p >> 3, pk = p & 7;
        int lk = pk ^ (row & 7);
        gA[rr] = A + (size_t)(m0 + row) * Cn + lk * 8;
    }
    #pragma unroll
    for (int rr = 0; rr < 2; ++rr) {
        int p = rr * 256 + tid;
        int row = p >> 3, pk = p & 7;
        int lk = pk ^ (row & 7);
        gW[rr] = W + (size_t)(n0 + row) * Cn + lk * 8;
    }

    f32x4 acc[4][2];
    #pragma unroll
    for (int mi = 0; mi < 4; ++mi)
        #pragma unroll
        for (int ni = 0; ni < 2; ++ni) acc[mi][ni] = (f32x4){0.f, 0.f, 0.f, 0.f};

    // prologue: prefetch k-step 0 into registers
    float4 va[4], vb[4], vc[2], vd[2];
    #pragma unroll
    for (int rr = 0; rr < 4; ++rr) {
        va[rr] = *(const float4*)gA[rr];
        vb[rr] = *(const float4*)(gA[rr] + 4);
        gA[rr] += BKg;
    }
    #pragma unroll
    for (int rr = 0; rr < 2; ++rr) {
        vc[rr] = *(const float4*)gW[rr];
        vd[rr] = *(const float4*)(gW[rr] + 4);
        gW[rr] += BKg;
    }

    for (int kt = 0; kt < Cn / BKg; ++kt) {
        // convert current step to fp16 (frees va/vb/vc/vd for the prefetch)
        h8 oa[4], ow[2];
        #pragma unroll
        for (int rr = 0; rr < 4; ++rr) {
            oa[rr][0] = (_Float16)va[rr].x; oa[rr][1] = (_Float16)va[rr].y;
            oa[rr][2] = (_Float16)va[rr].z; oa[rr][3] = (_Float16)va[rr].w;
            oa[rr][4] = (_Float16)vb[rr].x; oa[rr][5] = (_Float16)vb[rr].y;
            oa[rr][6] = (_Float16)vb[rr].z; oa[rr][7] = (_Float16)vb[rr].w;
        }
        #pragma unroll
        for (int rr = 0; rr < 2; ++rr) {
            ow[rr][0] = (_Float16)vc[rr].x; ow[rr][1] = (_Float16)vc[rr].y;
            ow[rr][2] = (_Float16)vc[rr].z; ow[rr][3] = (_Float16)vc[rr].w;
            ow[rr][4] = (_Float16)vd[rr].x; ow[rr][5] = (_Float16)vd[rr].y;
            ow[rr][6] = (_Float16)vd[rr].z; ow[rr][7] = (_Float16)vd[rr].w;
        }

        __syncthreads();   // previous step's LDS consumers are done

        // issue next step's global loads now: they land during this step's MFMAs
        if (kt + 1 < Cn / BKg) {
            #pragma unroll
            for (int rr = 0; rr < 4; ++rr) {
                va[rr] = *(const float4*)gA[rr];
                vb[rr] = *(const float4*)(gA[rr] + 4);
                gA[rr] += BKg;
            }
            #pragma unroll
            for (int rr = 0; rr < 2; ++rr) {
                vc[rr] = *(const float4*)gW[rr];
                vd[rr] = *(const float4*)(gW[rr] + 4);
                gW[rr] += BKg;
            }
        }

        #pragma unroll
        for (int rr = 0; rr < 4; ++rr)
            *(h8*)&As[(rr * 256 + tid) * 8] = oa[rr];
        #pragma unroll
        for (int rr = 0; rr < 2; ++rr)
            *(h8*)&Ws[(rr * 256 + tid) * 8] = ow[rr];
        __syncthreads();

        h8 af[4][2], bfr[2][2];
        #pragma unroll
        for (int mi = 0; mi < 4; ++mi)
            #pragma unroll
            for (int kk = 0; kk < 2; ++kk) {
                int row = wm + mi * 16 + r;
                int phys = (kk * 4 + q) ^ (r & 7);
                af[mi][kk] = *(const h8*)&As[row * BKg + phys * 8];
            }
        #pragma unroll
        for (int ni = 0; ni < 2; ++ni)
            #pragma unroll
            for (int kk = 0; kk < 2; ++kk) {
                int row = wn + ni * 16 + r;
                int phys = (kk * 4 + q) ^ (r & 7);
                bfr[ni][kk] = *(const h8*)&Ws[row * BKg + phys * 8];
            }
        #pragma unroll
        for (int kk = 0; kk < 2; ++kk)
            #pragma unroll
            for (int mi = 0; mi < 4; ++mi)
                #pragma unroll
                for (int ni = 0; ni < 2; ++ni)
                    acc[mi][ni] = __builtin_amdgcn_mfma_f32_16x16x32_f16(
                        af[mi][kk], bfr[ni][kk], acc[mi][ni], 0, 0, 0);
    }

    #pragma unroll
    for (int ni = 0; ni < 2; ++ni) {
        const float bv = bias[n0 + wn + ni * 16 + r];
        #pragma unroll
        for (int mi = 0; mi < 4; ++mi)
            #pragma unroll
            for (int reg = 0; reg < 4; ++reg) {
                int row = m0 + wm + mi * 16 + q * 4 + reg;
                int col = n0 + wn + ni * 16 + r;
                wf[(size_t)row * Cn + col] = (_Float16)(acc[mi][ni][reg] + bv);
            }
    }
}

// K2: scores via exp form of tanh addition:
//   sum_c aw*tanh(w+p) = sum_c aw - 2*sum_c aw*rcp(1 + e^{2w} e^{2p})
// The sum_c aw constant (and atten_b) is t-invariant -> cancels in softmax.
__global__ __launch_bounds__(512) void k_scores(
        const _Float16* __restrict__ wf, const float* __restrict__ EP,
        const float* __restrict__ aw, float* __restrict__ scores) {
    __shared__ float part[4 * Ln * 8];       // 3.2 KB
    const int tid  = threadIdx.x;
    const int lane = tid & 63;
    const int wv   = tid >> 6;
    const int tl   = wv >> 1;                // local t 0..3
    const int ch   = wv & 1;                 // c half
    const int t    = blockIdx.x * 4 + tl;
    const int b    = blockIdx.y;
    const int co   = ch * 256 + lane * 4;

    const h4 wh = *(const h4*)&wf[(size_t)(b * Tn + t) * Cn + co];
    float4 ew;
    ew.x = EXP2(SCALE2LOG2E * (float)wh[0]);
    ew.y = EXP2(SCALE2LOG2E * (float)wh[1]);
    ew.z = EXP2(SCALE2LOG2E * (float)wh[2]);
    ew.w = EXP2(SCALE2LOG2E * (float)wh[3]);
    float4 a = *(const float4*)&aw[co];
    a.x *= -2.f; a.y *= -2.f; a.z *= -2.f; a.w *= -2.f;

    const float* pp = EP + co;
    float* prt = &part[tl * Ln * 8 + ch * 4 + (lane >> 4)];
    const bool writer = ((lane & 15) == 0);

    #pragma unroll
    for (int lo = 0; lo < 5; ++lo) {
        float4 pv[5];
        #pragma unroll
        for (int j = 0; j < 5; ++j)
            pv[j] = *(const float4*)(pp + (lo * 5 + j) * Cn);
        #pragma unroll
        for (int j = 0; j < 5; ++j) {
            const float4 p = pv[j];
            float d0 = fmaf(ew.x, p.x, 1.f);
            float s  = a.x * __builtin_amdgcn_rcpf(d0);
            float d1 = fmaf(ew.y, p.y, 1.f);
            s = fmaf(a.y, __builtin_amdgcn_rcpf(d1), s);
            float d2 = fmaf(ew.z, p.z, 1.f);
            s = fmaf(a.z, __builtin_amdgcn_rcpf(d2), s);
            float d3 = fmaf(ew.w, p.w, 1.f);
            s = fmaf(a.w, __builtin_amdgcn_rcpf(d3), s);
            s = DPP_ADD(s, 0xB1);    // xor 1
            s = DPP_ADD(s, 0x4E);    // xor 2
            s = DPP_ADD(s, 0x141);   // row_half_mirror (xor 7)
            s = DPP_ADD(s, 0x140);   // row_mirror (xor 15)
            if (writer) prt[(lo * 5 + j) * 8] = s;
        }
    }
    __syncthreads();
    if (tid < 4 * Ln) {
        int tl2 = tid / Ln, l2 = tid - tl2 * Ln;
        const float* q = &part[(tl2 * Ln + l2) * 8];
        float v = ((q[0] + q[1]) + (q[2] + q[3])) + ((q[4] + q[5]) + (q[6] + q[7]));
        scores[(b * Ln + l2) * Tn + blockIdx.x * 4 + tl2] = v;
    }
}

// K3: softmax over t; out[b][l][c] = sum_t p[l][t] * wf[b][t][c]; wf fp16 reads.
__global__ __launch_bounds__(512) void k_pvam(
        const _Float16* __restrict__ wf, const float* __restrict__ scores,
        float* __restrict__ out) {
    __shared__ float buf[8 * Ln * 64];       // 51.2 KB: scores staging, then reduction
    __shared__ float pT[Tn][28];             // 28.7 KB
    const int tid = threadIdx.x;
    const int cx  = blockIdx.x;
    const int b   = blockIdx.y;

    const float* sc = scores + b * Ln * Tn;
    for (int i = tid * 4; i < Ln * Tn; i += 2048)
        *(float4*)&buf[i] = *(const float4*)&sc[i];
    __syncthreads();

    const int lane = tid & 63;
    const int wv   = tid >> 6;

    for (int l = wv; l < Ln; l += 8) {
        float v0 = buf[l * Tn + lane];
        float v1 = buf[l * Tn + 64 + lane];
        float v2 = buf[l * Tn + 128 + lane];
        float v3 = buf[l * Tn + 192 + lane];
        float m = fmaxf(fmaxf(v0, v1), fmaxf(v2, v3));
        #pragma unroll
        for (int o = 32; o > 0; o >>= 1) m = fmaxf(m, __shfl_xor(m, o));
        float e0 = __expf(v0 - m), e1 = __expf(v1 - m);
        float e2 = __expf(v2 - m), e3 = __expf(v3 - m);
        float s = e0 + e1 + e2 + e3;
        #pragma unroll
        for (int o = 32; o > 0; o >>= 1) s += __shfl_xor(s, o);
        float rs = __builtin_amdgcn_rcpf(s);
        pT[lane][l]       = e0 * rs;
        pT[64 + lane][l]  = e1 * rs;
        pT[128 + lane][l] = e2 * rs;
        pT[192 + lane][l] = e3 * rs;
    }
    __syncthreads();

    const int c = cx * 64 + lane;
    float acc[Ln];
    #pragma unroll
    for (int l = 0; l < Ln; ++l) acc[l] = 0.f;

    const _Float16* wfp = wf + (size_t)(b * Tn + wv * 32) * Cn + c;
    for (int tt = 0; tt < 32; ++tt) {
        float w = (float)wfp[(size_t)tt * Cn];
        const float* pp = &pT[wv * 32 + tt][0];
        float p[Ln];
        *(float4*)&p[0]  = *(const float4*)&pp[0];
        *(float4*)&p[4]  = *(const float4*)&pp[4];
        *(float4*)&p[8]  = *(const float4*)&pp[8];
        *(float4*)&p[12] = *(const float4*)&pp[12];
        *(float4*)&p[16] = *(const float4*)&pp[16];
        *(float4*)&p[20] = *(const float4*)&pp[20];
        p[24] = pp[24];
        #pragma unroll
        for (int l = 0; l < Ln; ++l) acc[l] = fmaf(p[l], w, acc[l]);
    }

    __syncthreads();
    #pragma unroll
    for (int l = 0; l < Ln; ++l)
        buf[(wv * Ln + l) * 64 + lane] = acc[l];
    __syncthreads();
    for (int idx = tid; idx < Ln * 64; idx += 512) {
        int l = idx >> 6, cc = idx & 63;
        float v = 0.f;
        #pragma unroll
        for (int w = 0; w < 8; ++w) v += buf[(w * Ln + l) * 64 + cc];
        out[(b * Ln + l) * Cn + cx * 64 + cc] = v;
    }
}

extern "C" void kernel_launch(void* const* d_in, const int* in_sizes, int n_in,
                              void* d_out, int out_size, void* d_ws, size_t ws_size,
                              hipStream_t stream) {
    const float* A    = (const float*)d_in[0];
    const float* W    = (const float*)d_in[1];
    const float* bias = (const float*)d_in[2];
    const float* pos  = (const float*)d_in[3];
    const float* aw   = (const float*)d_in[4];

    char* ws = (char*)d_ws;
    _Float16*  wf     = (_Float16*)ws;                       // 8.39 MB
    float*     scores = (float*)(ws + 8388608ull);           // 0.82 MB
    float*     EP     = (float*)(ws + 9207808ull);           // 51.2 KB exp(2*pos)
    float* out = (float*)d_out;

    k_gemm<<<dim3((Cn / BN) * ((Bn * Tn) / BM)), 256, 0, stream>>>(A, W, bias, pos, wf, EP);
    k_scores<<<dim3(Tn / 4, Bn), 512, 0, stream>>>(wf, EP, aw, scores);
    k_pvam<<<dim3(Cn / 64, Bn), 512, 0, stream>>>(wf, scores, out);
}